// Round 4
// baseline (276.412 us; speedup 1.0000x reference)
//
#include <hip/hip_runtime.h>
#include <math.h>

#define BB 32
#define SS 2048
#define DD 512
#define AD 512

#define BM 128
#define BN 128
#define BK 32    // bf16 elems per K-chunk; row = 64 B = 4 x 16B granules

typedef __bf16 bf16;
typedef __attribute__((ext_vector_type(8))) __bf16 bf16x8;
typedef __attribute__((ext_vector_type(4))) __bf16 bf16x4;
typedef __attribute__((ext_vector_type(4))) float floatx4;

__device__ inline void async16(const void* g, void* l) {
    __builtin_amdgcn_global_load_lds(
        (const __attribute__((address_space(1))) unsigned int*)g,
        (__attribute__((address_space(3))) unsigned int*)l, 16, 0, 0);
}

// ---------------- K0: probe mask dtype ----------------
__global__ void mask_probe_kernel(const unsigned char* __restrict__ m8,
                                  int* __restrict__ flag) {
    int t = threadIdx.x + blockIdx.x * 256;
    int any = 0;
    for (int i = t; i < BB * SS; i += gridDim.x * 256) {
        if ((i & 3) && m8[i]) any = 1;
    }
    if (__any(any)) {
        if ((threadIdx.x & 63) == 0) atomicOr(flag, 1);
    }
}

// ---------------- K0b: fp32 -> bf16 convert (memory-bound) ----------------
__global__ void convert_kernel(const float* __restrict__ src,
                               bf16* __restrict__ dst, int n8) {
    int i = threadIdx.x + blockIdx.x * 256;
    if (i >= n8) return;
    const float4* s4 = (const float4*)src + (size_t)i * 2;
    float4 x = s4[0], y = s4[1];
    bf16x8 o;
    o[0] = (bf16)x.x; o[1] = (bf16)x.y; o[2] = (bf16)x.z; o[3] = (bf16)x.w;
    o[4] = (bf16)y.x; o[5] = (bf16)y.y; o[6] = (bf16)y.z; o[7] = (bf16)y.w;
    *(bf16x8*)(dst + (size_t)i * 8) = o;
}

// ---------------- K1: w1q[b][a] = dot(query[b,:], W1[a,:]) (fp32) ----------
__global__ void w1q_kernel(const float* __restrict__ query,
                           const float* __restrict__ W1,
                           float* __restrict__ w1q) {
    int b = blockIdx.y;
    int a = blockIdx.x * 4 + (threadIdx.x >> 6);
    int lane = threadIdx.x & 63;
    const float4* q4 = (const float4*)(query + (size_t)b * DD) + lane * 2;
    const float4* w4 = (const float4*)(W1 + (size_t)a * DD) + lane * 2;
    float4 qa = q4[0], qb = q4[1];
    float4 wa = w4[0], wb = w4[1];
    float acc = qa.x * wa.x + qa.y * wa.y + qa.z * wa.z + qa.w * wa.w
              + qb.x * wb.x + qb.y * wb.y + qb.z * wb.z + qb.w * wb.w;
#pragma unroll
    for (int off = 32; off > 0; off >>= 1) acc += __shfl_down(acc, off);
    if (lane == 0) w1q[(size_t)b * AD + a] = acc;
}

// ---------------- K2: dbuf MFMA GEMM + fused tanh/v epilogue --------------
// A = keys_bf16, B = W2_bf16, both [rows x 512] row-major.
// grid (AD/BN, SS/BM, BB): a-tile fastest so the 4 blocks sharing a keys
// tile are dispatch-adjacent (L2). 256 thr = 4 waves, wave = 64x64.
// Double-buffered LDS, ONE barrier per K-chunk; next chunk's async16 issued
// BEFORE this chunk's MFMA so the vmcnt drain at the barrier has ~full
// MFMA-phase latency cover. 16B-granule XOR swizzle c^(r&3): frag reads are
// a permutation of a contiguous 1KB region -> conflict-free.
__global__ __launch_bounds__(256, 4)
void gemm_scores_mfma(const bf16* __restrict__ keysb,
                      const bf16* __restrict__ W2b,
                      const float* __restrict__ w1q,
                      const float* __restrict__ v,
                      float* __restrict__ partial) {
    __shared__ bf16 a_lds[2][BM * BK];
    __shared__ bf16 b_lds[2][BN * BK];
    __shared__ float s_red[BM];

    const int t    = threadIdx.x;
    const int lane = t & 63;
    const int w    = t >> 6;
    const int ml   = lane & 15;
    const int kg   = lane >> 4;
    const int b    = blockIdx.z;
    const int a0   = blockIdx.x * BN;
    const int s0   = blockIdx.y * BM;
    const int m_off = (w & 1) * 64;
    const int n_off = (w >> 1) * 64;

    const bf16* Ablk = keysb + ((size_t)b * SS + s0) * DD;
    const bf16* Bblk = W2b + (size_t)a0 * DD;

    if (t < BM) s_red[t] = 0.f;

    floatx4 acc[4][4];
#pragma unroll
    for (int mi = 0; mi < 4; ++mi)
#pragma unroll
        for (int ni = 0; ni < 4; ++ni)
            acc[mi][ni] = (floatx4)(0.f);

    // staging: lane's dst granule lin = w*128 + i*64 + lane (granule = 16B).
    // row r = lin>>2, granule-in-row cc = lin&3, swizzled src granule cc^(r&3).
    const int NCHUNK = DD / BK;   // 16

    // prologue: stage chunk 0 into buf 0
#pragma unroll
    for (int i = 0; i < 2; ++i) {
        int lin = w * 128 + i * 64 + lane;
        int r = lin >> 2, cc = lin & 3, cs = cc ^ (r & 3);
        async16(Ablk + (size_t)r * DD + cs * 8, &a_lds[0][(w * 128 + i * 64) * 8]);
        async16(Bblk + (size_t)r * DD + cs * 8, &b_lds[0][(w * 128 + i * 64) * 8]);
    }
    __syncthreads();

    for (int c = 0; c < NCHUNK; ++c) {
        const int cur = c & 1;
        if (c + 1 < NCHUNK) {
            const int d0 = (c + 1) * BK;
            const int nxt = (c + 1) & 1;
#pragma unroll
            for (int i = 0; i < 2; ++i) {
                int lin = w * 128 + i * 64 + lane;
                int r = lin >> 2, cc = lin & 3, cs = cc ^ (r & 3);
                async16(Ablk + (size_t)r * DD + d0 + cs * 8,
                        &a_lds[nxt][(w * 128 + i * 64) * 8]);
                async16(Bblk + (size_t)r * DD + d0 + cs * 8,
                        &b_lds[nxt][(w * 128 + i * 64) * 8]);
            }
        }

        bf16x8 af[4], bfr[4];
#pragma unroll
        for (int mi = 0; mi < 4; ++mi) {
            int R = m_off + mi * 16 + ml;
            af[mi] = *(const bf16x8*)&a_lds[cur][R * BK + (kg ^ (R & 3)) * 8];
        }
#pragma unroll
        for (int ni = 0; ni < 4; ++ni) {
            int R = n_off + ni * 16 + ml;
            bfr[ni] = *(const bf16x8*)&b_lds[cur][R * BK + (kg ^ (R & 3)) * 8];
        }
#pragma unroll
        for (int mi = 0; mi < 4; ++mi)
#pragma unroll
            for (int ni = 0; ni < 4; ++ni)
                acc[mi][ni] = __builtin_amdgcn_mfma_f32_16x16x32_bf16(
                    af[mi], bfr[ni], acc[mi][ni], 0, 0, 0);

        __syncthreads();   // drains prefetch vmcnt (covered by MFMA phase) +
                           // guards buf reuse
    }

    // epilogue: tanh + v-weight, reduce over this block's 128 a's per s
    float w1qa[4], va[4];
#pragma unroll
    for (int ni = 0; ni < 4; ++ni) {
        int a = a0 + n_off + ni * 16 + ml;
        w1qa[ni] = w1q[(size_t)b * AD + a];
        va[ni]   = v[a];
    }
#pragma unroll
    for (int mi = 0; mi < 4; ++mi) {
#pragma unroll
        for (int reg = 0; reg < 4; ++reg) {
            float p = 0.f;
#pragma unroll
            for (int ni = 0; ni < 4; ++ni) {
                float x = acc[mi][ni][reg] + w1qa[ni];
                float th = 1.f - 2.f / (1.f + __expf(2.f * x));
                p = fmaf(th, va[ni], p);
            }
            p += __shfl_xor(p, 1);
            p += __shfl_xor(p, 2);
            p += __shfl_xor(p, 4);
            p += __shfl_xor(p, 8);
            if (ml == 0)
                atomicAdd(&s_red[m_off + mi * 16 + kg * 4 + reg], p);
        }
    }
    __syncthreads();
    if (t < BM)
        partial[(((size_t)b * SS) + s0 + t) * 4 + blockIdx.x] = s_red[t];
}

// ---------------- K2-fallback (round-2 fused-convert kernel) --------------
#define FBK 32
#define FLDK (FBK + 8)
__global__ __launch_bounds__(256, 2)
void gemm_scores_fallback(const float* __restrict__ keys,
                          const float* __restrict__ W2,
                          const float* __restrict__ w1q,
                          const float* __restrict__ v,
                          float* __restrict__ partial) {
    __shared__ bf16 a_lds[BM][FLDK];
    __shared__ bf16 b_lds[BN][FLDK];
    __shared__ float s_red[BM];

    const int t    = threadIdx.x;
    const int lane = t & 63;
    const int w    = t >> 6;
    const int ml   = lane & 15;
    const int kg   = lane >> 4;
    const int b    = blockIdx.z;
    const int s0   = blockIdx.x * BM;
    const int a0   = blockIdx.y * BN;
    const int m_off = (w & 1) * 64;
    const int n_off = (w >> 1) * 64;

    const float* Ablk = keys + ((size_t)b * SS + s0) * DD;
    const float* Bblk = W2 + (size_t)a0 * DD;

    if (t < BM) s_red[t] = 0.f;

    floatx4 acc[4][4];
#pragma unroll
    for (int mi = 0; mi < 4; ++mi)
#pragma unroll
        for (int ni = 0; ni < 4; ++ni)
            acc[mi][ni] = (floatx4)(0.f);

    float4 ga[4], gb[4];
#pragma unroll
    for (int i = 0; i < 4; ++i) {
        int idx = t + 256 * i;
        int r = idx >> 3, c = idx & 7;
        ga[i] = *(const float4*)(Ablk + (size_t)r * DD + c * 4);
        gb[i] = *(const float4*)(Bblk + (size_t)r * DD + c * 4);
    }

    for (int chunk = 0; chunk < DD / FBK; ++chunk) {
        __syncthreads();
#pragma unroll
        for (int i = 0; i < 4; ++i) {
            int idx = t + 256 * i;
            int r = idx >> 3, c = idx & 7;
            bf16x4 pa, pb;
            pa[0] = (bf16)ga[i].x; pa[1] = (bf16)ga[i].y;
            pa[2] = (bf16)ga[i].z; pa[3] = (bf16)ga[i].w;
            pb[0] = (bf16)gb[i].x; pb[1] = (bf16)gb[i].y;
            pb[2] = (bf16)gb[i].z; pb[3] = (bf16)gb[i].w;
            *(bf16x4*)&a_lds[r][c * 4] = pa;
            *(bf16x4*)&b_lds[r][c * 4] = pb;
        }
        __syncthreads();
        if (chunk < DD / FBK - 1) {
            int d0 = (chunk + 1) * FBK;
#pragma unroll
            for (int i = 0; i < 4; ++i) {
                int idx = t + 256 * i;
                int r = idx >> 3, c = idx & 7;
                ga[i] = *(const float4*)(Ablk + (size_t)r * DD + d0 + c * 4);
                gb[i] = *(const float4*)(Bblk + (size_t)r * DD + d0 + c * 4);
            }
        }
        bf16x8 af[4], bfr[4];
#pragma unroll
        for (int mi = 0; mi < 4; ++mi)
            af[mi] = *(const bf16x8*)&a_lds[m_off + mi * 16 + ml][kg * 8];
#pragma unroll
        for (int ni = 0; ni < 4; ++ni)
            bfr[ni] = *(const bf16x8*)&b_lds[n_off + ni * 16 + ml][kg * 8];
#pragma unroll
        for (int mi = 0; mi < 4; ++mi)
#pragma unroll
            for (int ni = 0; ni < 4; ++ni)
                acc[mi][ni] = __builtin_amdgcn_mfma_f32_16x16x32_bf16(
                    af[mi], bfr[ni], acc[mi][ni], 0, 0, 0);
    }

    float w1qa[4], va[4];
#pragma unroll
    for (int ni = 0; ni < 4; ++ni) {
        int a = a0 + n_off + ni * 16 + ml;
        w1qa[ni] = w1q[(size_t)b * AD + a];
        va[ni]   = v[a];
    }
#pragma unroll
    for (int mi = 0; mi < 4; ++mi) {
#pragma unroll
        for (int reg = 0; reg < 4; ++reg) {
            float p = 0.f;
#pragma unroll
            for (int ni = 0; ni < 4; ++ni) {
                float x = acc[mi][ni][reg] + w1qa[ni];
                float th = 1.f - 2.f / (1.f + __expf(2.f * x));
                p = fmaf(th, va[ni], p);
            }
            p += __shfl_xor(p, 1);
            p += __shfl_xor(p, 2);
            p += __shfl_xor(p, 4);
            p += __shfl_xor(p, 8);
            if (ml == 0)
                atomicAdd(&s_red[m_off + mi * 16 + kg * 4 + reg], p);
        }
    }
    __syncthreads();
    if (t < BM)
        partial[(((size_t)b * SS) + s0 + t) * 4 + blockIdx.y] = s_red[t];
}

// ---------------- K3: combine partials + masked softmax over s ------------
__global__ void softmax_kernel(const float* __restrict__ partial,
                               const int* __restrict__ mask_i32,
                               const unsigned char* __restrict__ mask_u8,
                               const int* __restrict__ flag,
                               float* __restrict__ out) {
    const int b = blockIdx.x;
    const int t = threadIdx.x;
    __shared__ float rmax[4], rsum[4];
    const int wid = t >> 6, lane = t & 63;

    float sv[8]; int mv[8];
    const int bytes = (*flag != 0);
#pragma unroll
    for (int k = 0; k < 8; ++k) {
        int i = t + 256 * k;
        float4 p4 = *(const float4*)(partial + ((size_t)b * SS + i) * 4);
        sv[k] = (p4.x + p4.y) + (p4.z + p4.w);
        mv[k] = bytes ? (int)mask_u8[(size_t)b * SS + i]
                      : mask_i32[(size_t)b * SS + i];
    }

    float mx = -INFINITY;
#pragma unroll
    for (int k = 0; k < 8; ++k) mx = fmaxf(mx, mv[k] ? sv[k] : -INFINITY);
#pragma unroll
    for (int off = 32; off > 0; off >>= 1) mx = fmaxf(mx, __shfl_xor(mx, off));
    if (lane == 0) rmax[wid] = mx;
    __syncthreads();
    mx = fmaxf(fmaxf(rmax[0], rmax[1]), fmaxf(rmax[2], rmax[3]));

    float ev[8]; float sum = 0.f;
#pragma unroll
    for (int k = 0; k < 8; ++k) {
        ev[k] = mv[k] ? __expf(sv[k] - mx) : 0.f;
        sum += ev[k];
    }
#pragma unroll
    for (int off = 32; off > 0; off >>= 1) sum += __shfl_xor(sum, off);
    if (lane == 0) rsum[wid] = sum;
    __syncthreads();
    sum = (rsum[0] + rsum[1]) + (rsum[2] + rsum[3]);
    float inv = 1.f / sum;
#pragma unroll
    for (int k = 0; k < 8; ++k)
        out[(size_t)b * SS + t + 256 * k] = ev[k] * inv;
}

extern "C" void kernel_launch(void* const* d_in, const int* in_sizes, int n_in,
                              void* d_out, int out_size, void* d_ws, size_t ws_size,
                              hipStream_t stream) {
    const float* query = (const float*)d_in[0];
    const float* keys  = (const float*)d_in[1];
    const void*  mask  = d_in[2];
    const float* W1    = (const float*)d_in[3];
    const float* W2    = (const float*)d_in[4];
    const float* v     = (const float*)d_in[5];
    float* out = (float*)d_out;

    // ws layout (bytes): [flag 256][w1q 64K][partial 1M][keysb 64M][W2b 0.5M]
    char* wsb = (char*)d_ws;
    int*   flag    = (int*)wsb;
    float* w1q     = (float*)(wsb + 256);
    float* partial = (float*)(wsb + 256 + 65536);
    bf16*  keysb   = (bf16*)(wsb + 256 + 65536 + 1048576);
    bf16*  W2b     = (bf16*)(wsb + 256 + 65536 + 1048576 + (size_t)BB * SS * DD * 2);
    size_t need = 256 + 65536 + 1048576 + (size_t)BB * SS * DD * 2 + (size_t)AD * DD * 2;

    hipMemsetAsync(flag, 0, 4, stream);
    mask_probe_kernel<<<64, 256, 0, stream>>>((const unsigned char*)mask, flag);
    w1q_kernel<<<dim3(AD / 4, BB), 256, 0, stream>>>(query, W1, w1q);

    if (ws_size >= need) {
        int nk8 = BB * SS * DD / 8;   // 4,194,304
        int nw8 = AD * DD / 8;        // 32,768
        convert_kernel<<<(nk8 + 255) / 256, 256, 0, stream>>>(keys, keysb, nk8);
        convert_kernel<<<(nw8 + 255) / 256, 256, 0, stream>>>(W2, W2b, nw8);
        gemm_scores_mfma<<<dim3(AD / BN, SS / BM, BB), 256, 0, stream>>>(
            keysb, W2b, w1q, v, partial);
    } else {
        gemm_scores_fallback<<<dim3(SS / BM, AD / BN, BB), 256, 0, stream>>>(
            keys, W2, w1q, v, partial);
    }
    softmax_kernel<<<BB, 256, 0, stream>>>(partial, (const int*)mask,
                                           (const unsigned char*)mask, flag, out);
}